// Round 6
// baseline (207.838 us; speedup 1.0000x reference)
//
#include <hip/hip_runtime.h>

// Involution (B=8, H=W=192, C=64, G=4, K=3, R=4) — round 10.
// R9 post-mortem: split FAILED (gen 55us + apply ~50us > fused 73us) but
// isolated the bottleneck: Phase A alone runs 55us vs 6us VALU / 22us mem
// floors at 18 waves/CU — intrinsically slow. Cause: thread=pixel mapping
// makes each x-load wave-inst touch 64 lanes x 16B at 256B stride = 64
// cache lines/inst (16x worse than coalesced), 16 insts/thread -> L1
// thrash + ~4x L2 request amplification (invisible in FETCH: L2/L3 absorb
// it). Present in every round so far; Phase B (c4i-minor, 1KB/inst) is
// the proof by contrast.
// R10: R6 fused + Phase A x-reads via LDS:
//   stage tile x (32KB) with 16 COALESCED 1KB/wave loads -> s_x, pixel
//   stride 17 float4 (68 words): bank-quad = (pixel+chunk)%8 is uniform
//   for both the staged writes and the per-pixel b128 reads (~conflict-
//   free). s_x dead after w1 loop -> s_kern (18KB) overwrites it behind a
//   barrier; peak LDS 34.8KB -> 4 blocks/CU.
// Phase B: R6 verbatim (mask-0 fences, 4-slot ring, (128,2)).
// GATES: WRITE == 73728 (no spill), VGPR 100-140, conflicts <1% LDS ops.
// dur 73 -> 45-60us if theory right; flat => weight s_load stream next.

#define B_   8
#define H_   192
#define W_   192
#define CR_  16
#define TH_  8
#define TW_  16
#define TILES_X (W_/TW_)                    // 12
#define TILES_PER_IMG (TILES_X*(H_/TH_))    // 288
#define NBLK (B_*TILES_PER_IMG)             // 2304
#define NPIX (TH_*TW_)                      // 128
#define XSTRIDE 17                          // float4/pixel in s_x (16+1 pad)

constexpr float BN_EPS = 1e-3f;

__device__ __forceinline__ float4 mask4(float4 k, bool v) {
    k.x = v ? k.x : 0.f;
    k.y = v ? k.y : 0.f;
    k.z = v ? k.z : 0.f;
    k.w = v ? k.w : 0.f;
    return k;
}

__device__ __forceinline__ void fma4(float4& a, const float4 k, const float4 x) {
    a.x = fmaf(k.x, x.x, a.x);
    a.y = fmaf(k.y, x.y, a.y);
    a.z = fmaf(k.z, x.z, a.z);
    a.w = fmaf(k.w, x.w, a.w);
}

// ---- Phase B: R6-proven column-walk (mask-0 fences, 4-slot ring) --------
#define LROWS(S, R)                                                         \
    do {                                                                    \
        int rr_ = (R);                                                      \
        if (!INTERIOR) {                                                    \
            if ((unsigned)rr_ < (unsigned)H_) rv |= (1 << (S));             \
            else                              rv &= ~(1 << (S));            \
            rr_ = rr_ < 0 ? 0 : (rr_ >= H_ ? H_ - 1 : rr_);                 \
        }                                                                   \
        const int rb_ = rr_ * (W_ * 16);                                    \
        rgA[S][0] = x4[rb_ + coA[0]];                                       \
        rgA[S][1] = x4[rb_ + coA[1]];                                       \
        rgA[S][2] = x4[rb_ + coA[2]];                                       \
        rgB[S][0] = x4[rb_ + coB[0]];                                       \
        rgB[S][1] = x4[rb_ + coB[1]];                                       \
        rgB[S][2] = x4[rb_ + coB[2]];                                       \
    } while (0)

#define COMP(I)                                                             \
    do {                                                                    \
        const float4* kqA_ = &s_kern[((I) * TW_ + wslot) * 9];              \
        const float4* kqB_ = &s_kern[((I) * TW_ + wslot + 8) * 9];          \
        float4 aA_ = make_float4(0.f, 0.f, 0.f, 0.f);                       \
        float4 aB_ = make_float4(0.f, 0.f, 0.f, 0.f);                       \
        _Pragma("unroll")                                                   \
        for (int ti_ = 0; ti_ < 3; ++ti_) {                                 \
            const int s_ = ((I) + ti_) & 3;                                 \
            _Pragma("unroll")                                               \
            for (int tj_ = 0; tj_ < 3; ++tj_) {                             \
                float4 kA_ = kqA_[ti_ * 3 + tj_];                           \
                float4 kB_ = kqB_[ti_ * 3 + tj_];                           \
                if (!INTERIOR) {                                            \
                    kA_ = mask4(kA_, (((rv >> s_) & (cmA >> tj_)) & 1));    \
                    kB_ = mask4(kB_, (((rv >> s_) & (cmB >> tj_)) & 1));    \
                }                                                           \
                fma4(aA_, kA_, rgA[s_][tj_]);                               \
                fma4(aB_, kB_, rgB[s_][tj_]);                               \
            }                                                               \
        }                                                                   \
        const int ob_ = (th0 + (I)) * (W_ * 16);                            \
        o4[ob_ + (wA << 4) + c4i] = aA_;                                    \
        o4[ob_ + (wB << 4) + c4i] = aB_;                                    \
    } while (0)

#define SFENCE __builtin_amdgcn_sched_barrier(0)

template <bool INTERIOR>
__device__ __forceinline__ void phase_b(const float4* __restrict__ x4,
                                        float4* __restrict__ o4,
                                        const float4* __restrict__ s_kern,
                                        int th0, int tw0, int tid)
{
    const int wslot = tid >> 4;   // 0..7 -> columns wslot and wslot+8
    const int c4i   = tid & 15;   // float4 channel chunk
    const int wA = tw0 + wslot;
    const int wB = tw0 + wslot + 8;

    int coA[3], coB[3];
    int cmA = 7, cmB = 7;
    #pragma unroll
    for (int tj = 0; tj < 3; ++tj) {
        int wa = wA + tj - 1;
        int wb = wB + tj - 1;
        if (!INTERIOR) {
            if ((unsigned)wa >= (unsigned)W_) cmA &= ~(1 << tj);
            if ((unsigned)wb >= (unsigned)W_) cmB &= ~(1 << tj);
            wa = wa < 0 ? 0 : (wa >= W_ ? W_ - 1 : wa);
            wb = wb < 0 ? 0 : (wb >= W_ ? W_ - 1 : wb);
        }
        coA[tj] = (wa << 4) + c4i;
        coB[tj] = (wb << 4) + c4i;
    }

    float4 rgA[4][3], rgB[4][3];   // 96 VGPR ring, all indices static
    int rv = 0xF;

    LROWS(0, th0 - 1);
    LROWS(1, th0 + 0);
    LROWS(2, th0 + 1);
    LROWS(3, th0 + 2);
    SFENCE;
    COMP(0); LROWS(0, th0 + 3);
    SFENCE;
    COMP(1); LROWS(1, th0 + 4);
    SFENCE;
    COMP(2); LROWS(2, th0 + 5);
    SFENCE;
    COMP(3); LROWS(3, th0 + 6);
    SFENCE;
    COMP(4); LROWS(0, th0 + 7);
    SFENCE;
    COMP(5); LROWS(1, th0 + 8);
    SFENCE;
    COMP(6);
    COMP(7);
}

#undef LROWS
#undef COMP

__global__ __launch_bounds__(128, 2)
void invol_fused(const float* __restrict__ x,
                 const float* __restrict__ w1,
                 const float* __restrict__ b1,
                 const float* __restrict__ gamma,
                 const float* __restrict__ beta,
                 const float* __restrict__ mean,
                 const float* __restrict__ var,
                 const float* __restrict__ w2,
                 const float* __restrict__ b2,
                 float* __restrict__ out)
{
    // Dual-use LDS: s_x [128 px][17 f4] = 34.8KB during Phase A, then
    // s_kern [128 px][9 f4] = 18KB overwrites it (behind a barrier).
    __shared__ float4 smem[NPIX * XSTRIDE];

    const int bid = blockIdx.x;
    // XCD swizzle: 2304 = 8 * 288; each XCD owns one image for L2 locality.
    const int img = bid & 7;
    const int tin = bid >> 3;
    const int th0 = (tin / TILES_X) * TH_;
    const int tw0 = (tin % TILES_X) * TW_;
    const int tid = threadIdx.x;

    const float4* x4 = reinterpret_cast<const float4*>(x) +
                       (size_t)img * (H_ * W_ * 16);
    float4* o4 = reinterpret_cast<float4*>(out) +
                 (size_t)img * (H_ * W_ * 16);

    // ---- Phase A0: coalesced x-tile stage -> LDS ------------------------
    // Tile row r: 16 px x 16 chunks = 256 float4 = 4KB contiguous in global.
    // Wave-inst: 64 consecutive float4 = 1KB contiguous (vs 64 scattered
    // lines in the old thread=pixel pattern). LDS addr quad (p+j)%8 uniform.
    {
        const int rowbase = th0 * (W_ * 16) + (tw0 << 4);
        #pragma unroll
        for (int i = 0; i < 16; ++i) {
            const int lin = i * 128 + tid;      // 0..2047
            const int r   = lin >> 8;           // tile row 0..7
            const int c   = lin & 255;          // float4 within row
            const float4 v = x4[rowbase + r * (W_ * 16) + c];
            smem[(r * 16 + (c >> 4)) * XSTRIDE + (c & 15)] = v;
        }
    }
    __syncthreads();

    // ---- Phase A1: per-pixel MLP (x reads now from LDS) -----------------
    float ke[36];
    {
        float td[CR_];
        #pragma unroll
        for (int d = 0; d < CR_; ++d) td[d] = 0.f;

        // t = x @ w1  (weight addresses wave-uniform -> s_load pipe)
        #pragma unroll
        for (int c4 = 0; c4 < 16; ++c4) {
            const float4 xv = smem[tid * XSTRIDE + c4];
            const float xs[4] = {xv.x, xv.y, xv.z, xv.w};
            #pragma unroll
            for (int k = 0; k < 4; ++k) {
                const float* wr = w1 + (c4 * 4 + k) * CR_;
                #pragma unroll
                for (int d = 0; d < CR_; ++d)
                    td[d] = fmaf(xs[k], wr[d], td[d]);
            }
        }

        __syncthreads();   // all s_x reads done; smem may be overwritten

        // + b1, BN (inference), ReLU — folded affine
        #pragma unroll
        for (int d = 0; d < CR_; ++d) {
            const float a = gamma[d] * rsqrtf(var[d] + BN_EPS);
            const float c = (b1[d] - mean[d]) * a + beta[d];
            td[d] = fmaxf(fmaf(td[d], a, c), 0.f);
        }

        // kern = t @ w2 + b2  (e = tap*4 + g)
        #pragma unroll
        for (int e = 0; e < 36; ++e) ke[e] = b2[e];
        #pragma unroll
        for (int d = 0; d < CR_; ++d) {
            const float t = td[d];
            const float* wr = w2 + d * 36;
            #pragma unroll
            for (int e = 0; e < 36; ++e)
                ke[e] = fmaf(t, wr[e], ke[e]);
        }
    }

    // ---- Phase A2: write s_kern (reuses the s_x LDS region) -------------
    {
        float4* skq = &smem[tid * 9];
        #pragma unroll
        for (int t9 = 0; t9 < 9; ++t9)
            skq[t9] = make_float4(ke[t9 * 4 + 0], ke[t9 * 4 + 1],
                                  ke[t9 * 4 + 2], ke[t9 * 4 + 3]);
    }

    __syncthreads();

    // ---- Phase B: 9-tap multiply-reduce, column walk (R6 verbatim) ------
    const float4* s_kern = smem;
    const bool interior = (th0 > 0) && (th0 + TH_ < H_) &&
                          (tw0 > 0) && (tw0 + TW_ < W_);
    if (interior)
        phase_b<true >(x4, o4, s_kern, th0, tw0, tid);
    else
        phase_b<false>(x4, o4, s_kern, th0, tw0, tid);
}

extern "C" void kernel_launch(void* const* d_in, const int* in_sizes, int n_in,
                              void* d_out, int out_size, void* d_ws, size_t ws_size,
                              hipStream_t stream) {
    const float* x     = (const float*)d_in[0];
    const float* w1    = (const float*)d_in[1];
    const float* b1    = (const float*)d_in[2];
    const float* gamma = (const float*)d_in[3];
    const float* beta  = (const float*)d_in[4];
    const float* mean  = (const float*)d_in[5];
    const float* var   = (const float*)d_in[6];
    const float* w2    = (const float*)d_in[7];
    const float* b2    = (const float*)d_in[8];
    float* out = (float*)d_out;

    invol_fused<<<dim3(NBLK), dim3(128), 0, stream>>>(
        x, w1, b1, gamma, beta, mean, var, w2, b2, out);
}

// Round 8
// 178.885 us; speedup vs baseline: 1.1619x; 1.1619x over previous
//
#include <hip/hip_runtime.h>

// Involution (B=8, H=W=192, C=64, G=4, K=3, R=4) — round 11 (resubmit;
// previous attempt hit an infra failure: container acquisition died twice,
// no pytest/profile output. Kernel re-audited: index algebra, barrier
// uniformity, same-wave LDS WAR ordering all verified sound).
// R10 post-mortem: gates all passed (VGPR 108, no spill, 0 conflicts) yet
// 73->108us: the block-wide barrier between x-stage and MLP serialized the
// per-block critical path; with few blocks resident, critical path IS
// throughput. R6 had hidden the strided loads under the w1 FMA chain.
// The coalescing diagnosis stands (R9: Phase A standalone = 55us = 9x its
// VALU floor; strided thread=pixel reads touch 64 lines/wave-inst vs 16).
// R11: WAVE-PRIVATE transpose staging — no new barriers. Each wave stages
// its own 64 pixels (16 coalesced 1KB loads of rows 4w..4w+3) into its
// private LDS region; ds ops within a wave are program-ordered, so the
// MLP ds_reads need no __syncthreads. Waves stay staggered. XOR swizzle
// slot = c4 ^ (p&7) instead of +1 pad: 8-way min aliasing (conflict-free
// for b128) on both sides, LDS stays 32KB -> 5 blocks/CU LDS cap.
// s_kern overlays each wave's own region (addr = (q>>6)*1024 + (q&63)*9);
// single pre-B barrier unchanged. Phase B = R6 verbatim (mask-0 fences,
// 4-slot ring), prologue loads issued before the barrier.
// GATES: LDS 32768; WRITE == 73728 (no spill); conflicts ~0; VGPR <= 128.
// dur 73 -> 50-62us if TA theory right; flat => weight s_load chain next.

#define B_   8
#define H_   192
#define W_   192
#define CR_  16
#define TH_  8
#define TW_  16
#define TILES_X (W_/TW_)                    // 12
#define TILES_PER_IMG (TILES_X*(H_/TH_))    // 288
#define NBLK (B_*TILES_PER_IMG)             // 2304
#define NPIX (TH_*TW_)                      // 128
#define WREG 1024                           // float4 per wave LDS region

constexpr float BN_EPS = 1e-3f;

__device__ __forceinline__ float4 mask4(float4 k, bool v) {
    k.x = v ? k.x : 0.f;
    k.y = v ? k.y : 0.f;
    k.z = v ? k.z : 0.f;
    k.w = v ? k.w : 0.f;
    return k;
}

__device__ __forceinline__ void fma4(float4& a, const float4 k, const float4 x) {
    a.x = fmaf(k.x, x.x, a.x);
    a.y = fmaf(k.y, x.y, a.y);
    a.z = fmaf(k.z, x.z, a.z);
    a.w = fmaf(k.w, x.w, a.w);
}

// ---- Phase B: R6-proven column-walk (mask-0 fences, 4-slot ring) --------
#define LROWS(S, R)                                                         \
    do {                                                                    \
        int rr_ = (R);                                                      \
        if (!INTERIOR) {                                                    \
            if ((unsigned)rr_ < (unsigned)H_) rv |= (1 << (S));             \
            else                              rv &= ~(1 << (S));            \
            rr_ = rr_ < 0 ? 0 : (rr_ >= H_ ? H_ - 1 : rr_);                 \
        }                                                                   \
        const int rb_ = rr_ * (W_ * 16);                                    \
        rgA[S][0] = x4[rb_ + coA[0]];                                       \
        rgA[S][1] = x4[rb_ + coA[1]];                                       \
        rgA[S][2] = x4[rb_ + coA[2]];                                       \
        rgB[S][0] = x4[rb_ + coB[0]];                                       \
        rgB[S][1] = x4[rb_ + coB[1]];                                       \
        rgB[S][2] = x4[rb_ + coB[2]];                                       \
    } while (0)

// s_kern lives wave-chunked: pixel q at smem[(q>>6)*WREG + (q&63)*9].
// For COMP(I): qA = I*16+wslot, qB = qA+8 -> region I>>2 (compile-time).
#define COMP(I)                                                             \
    do {                                                                    \
        const float4* kqA_ = &s_kern[((I) >> 2) * WREG +                    \
                                     (((I) & 3) * TW_ + wslot) * 9];        \
        const float4* kqB_ = &s_kern[((I) >> 2) * WREG +                    \
                                     (((I) & 3) * TW_ + wslot + 8) * 9];    \
        float4 aA_ = make_float4(0.f, 0.f, 0.f, 0.f);                       \
        float4 aB_ = make_float4(0.f, 0.f, 0.f, 0.f);                       \
        _Pragma("unroll")                                                   \
        for (int ti_ = 0; ti_ < 3; ++ti_) {                                 \
            const int s_ = ((I) + ti_) & 3;                                 \
            _Pragma("unroll")                                               \
            for (int tj_ = 0; tj_ < 3; ++tj_) {                             \
                float4 kA_ = kqA_[ti_ * 3 + tj_];                           \
                float4 kB_ = kqB_[ti_ * 3 + tj_];                           \
                if (!INTERIOR) {                                            \
                    kA_ = mask4(kA_, (((rv >> s_) & (cmA >> tj_)) & 1));    \
                    kB_ = mask4(kB_, (((rv >> s_) & (cmB >> tj_)) & 1));    \
                }                                                           \
                fma4(aA_, kA_, rgA[s_][tj_]);                               \
                fma4(aB_, kB_, rgB[s_][tj_]);                               \
            }                                                               \
        }                                                                   \
        const int ob_ = (th0 + (I)) * (W_ * 16);                            \
        o4[ob_ + (wA << 4) + c4i] = aA_;                                    \
        o4[ob_ + (wB << 4) + c4i] = aB_;                                    \
    } while (0)

#define SFENCE __builtin_amdgcn_sched_barrier(0)

template <bool INTERIOR>
__device__ __forceinline__ void phase_b(const float4* __restrict__ x4,
                                        float4* __restrict__ o4,
                                        const float4* __restrict__ s_kern,
                                        int th0, int tw0, int tid)
{
    const int wslot = tid >> 4;   // 0..7 -> columns wslot and wslot+8
    const int c4i   = tid & 15;   // float4 channel chunk
    const int wA = tw0 + wslot;
    const int wB = tw0 + wslot + 8;

    int coA[3], coB[3];
    int cmA = 7, cmB = 7;
    #pragma unroll
    for (int tj = 0; tj < 3; ++tj) {
        int wa = wA + tj - 1;
        int wb = wB + tj - 1;
        if (!INTERIOR) {
            if ((unsigned)wa >= (unsigned)W_) cmA &= ~(1 << tj);
            if ((unsigned)wb >= (unsigned)W_) cmB &= ~(1 << tj);
            wa = wa < 0 ? 0 : (wa >= W_ ? W_ - 1 : wa);
            wb = wb < 0 ? 0 : (wb >= W_ ? W_ - 1 : wb);
        }
        coA[tj] = (wa << 4) + c4i;
        coB[tj] = (wb << 4) + c4i;
    }

    float4 rgA[4][3], rgB[4][3];   // 96 VGPR ring, all indices static
    int rv = 0xF;

    // Prologue loads BEFORE the barrier: stream while the other wave
    // finishes Phase A (global-only, no LDS dependence).
    LROWS(0, th0 - 1);
    LROWS(1, th0 + 0);
    LROWS(2, th0 + 1);
    LROWS(3, th0 + 2);

    __syncthreads();   // s_kern (both waves) now visible

    SFENCE;
    COMP(0); LROWS(0, th0 + 3);
    SFENCE;
    COMP(1); LROWS(1, th0 + 4);
    SFENCE;
    COMP(2); LROWS(2, th0 + 5);
    SFENCE;
    COMP(3); LROWS(3, th0 + 6);
    SFENCE;
    COMP(4); LROWS(0, th0 + 7);
    SFENCE;
    COMP(5); LROWS(1, th0 + 8);
    SFENCE;
    COMP(6);
    COMP(7);
}

#undef LROWS
#undef COMP

__global__ __launch_bounds__(128, 2)
void invol_fused(const float* __restrict__ x,
                 const float* __restrict__ w1,
                 const float* __restrict__ b1,
                 const float* __restrict__ gamma,
                 const float* __restrict__ beta,
                 const float* __restrict__ mean,
                 const float* __restrict__ var,
                 const float* __restrict__ w2,
                 const float* __restrict__ b2,
                 float* __restrict__ out)
{
    // Two wave-private 16KB regions. During A: wave w's s_x (64px x 16 f4,
    // XOR-swizzled). After A: wave w's s_kern (64px x 9 f4) overlays its
    // own region — no cross-wave hazard until the single pre-B barrier.
    __shared__ float4 smem[2 * WREG];   // 32 KB

    const int bid = blockIdx.x;
    // XCD swizzle: 2304 = 8 * 288; each XCD owns one image for L2 locality.
    const int img = bid & 7;
    const int tin = bid >> 3;
    const int th0 = (tin / TILES_X) * TH_;
    const int tw0 = (tin % TILES_X) * TW_;
    const int tid = threadIdx.x;
    const int wv  = tid >> 6;            // wave 0/1
    const int ln  = tid & 63;            // lane

    const float4* x4 = reinterpret_cast<const float4*>(x) +
                       (size_t)img * (H_ * W_ * 16);
    float4* o4 = reinterpret_cast<float4*>(out) +
                 (size_t)img * (H_ * W_ * 16);

    // ---- Phase A0: wave-private coalesced transpose stage (NO barrier) --
    // Wave w stages tile rows 4w..4w+3 (its own 64 pixels): 16 insts of
    // 64 consecutive float4 (1KB, 16 lines) each. ds_write transposed with
    // XOR swizzle slot = c4 ^ (p&7): 8-way min aliasing (conflict-free).
    {
        float4* sx = &smem[wv * WREG];
        const int rowbase = (th0 + 4 * wv) * (W_ * 16) + (tw0 << 4);
        #pragma unroll
        for (int i = 0; i < 16; ++i) {
            const float4 v = x4[rowbase + (i >> 2) * (W_ * 16) +
                                (i & 3) * 64 + ln];
            const int p = 4 * i + (ln >> 4);        // local pixel 0..63
            sx[p * 16 + ((ln & 15) ^ (p & 7))] = v;
        }
    }
    // Wave-internal ds ordering (program order + lgkmcnt) makes the stage
    // visible to this wave's reads below — no __syncthreads.

    // ---- Phase A1: per-pixel MLP, x from LDS --------------------------
    float ke[36];
    {
        const float4* sx = &smem[wv * WREG + ln * 16];
        const int sw = ln & 7;
        float td[CR_];
        #pragma unroll
        for (int d = 0; d < CR_; ++d) td[d] = 0.f;

        // t = x @ w1  (weight addresses wave-uniform -> s_load pipe)
        #pragma unroll
        for (int c4 = 0; c4 < 16; ++c4) {
            const float4 xv = sx[c4 ^ sw];          // logical chunk c4
            const float xs[4] = {xv.x, xv.y, xv.z, xv.w};
            #pragma unroll
            for (int k = 0; k < 4; ++k) {
                const float* wr = w1 + (c4 * 4 + k) * CR_;
                #pragma unroll
                for (int d = 0; d < CR_; ++d)
                    td[d] = fmaf(xs[k], wr[d], td[d]);
            }
        }

        // + b1, BN (inference), ReLU — folded affine
        #pragma unroll
        for (int d = 0; d < CR_; ++d) {
            const float a = gamma[d] * rsqrtf(var[d] + BN_EPS);
            const float c = (b1[d] - mean[d]) * a + beta[d];
            td[d] = fmaxf(fmaf(td[d], a, c), 0.f);
        }

        // kern = t @ w2 + b2  (e = tap*4 + g)
        #pragma unroll
        for (int e = 0; e < 36; ++e) ke[e] = b2[e];
        #pragma unroll
        for (int d = 0; d < CR_; ++d) {
            const float t = td[d];
            const float* wr = w2 + d * 36;
            #pragma unroll
            for (int e = 0; e < 36; ++e)
                ke[e] = fmaf(t, wr[e], ke[e]);
        }
    }

    // ---- Phase A2: s_kern into this wave's OWN region ------------------
    // (own s_x reads are complete in program order; other wave never
    // touches this region until after the barrier)
    {
        float4* skq = &smem[wv * WREG + ln * 9];
        #pragma unroll
        for (int t9 = 0; t9 < 9; ++t9)
            skq[t9] = make_float4(ke[t9 * 4 + 0], ke[t9 * 4 + 1],
                                  ke[t9 * 4 + 2], ke[t9 * 4 + 3]);
    }

    // ---- Phase B: 9-tap multiply-reduce, column walk (R6 verbatim; the
    // single __syncthreads lives inside, after the B-prologue loads) -----
    const bool interior = (th0 > 0) && (th0 + TH_ < H_) &&
                          (tw0 > 0) && (tw0 + TW_ < W_);
    if (interior)
        phase_b<true >(x4, o4, smem, th0, tw0, tid);
    else
        phase_b<false>(x4, o4, smem, th0, tw0, tid);
}

extern "C" void kernel_launch(void* const* d_in, const int* in_sizes, int n_in,
                              void* d_out, int out_size, void* d_ws, size_t ws_size,
                              hipStream_t stream) {
    const float* x     = (const float*)d_in[0];
    const float* w1    = (const float*)d_in[1];
    const float* b1    = (const float*)d_in[2];
    const float* gamma = (const float*)d_in[3];
    const float* beta  = (const float*)d_in[4];
    const float* mean  = (const float*)d_in[5];
    const float* var   = (const float*)d_in[6];
    const float* w2    = (const float*)d_in[7];
    const float* b2    = (const float*)d_in[8];
    float* out = (float*)d_out;

    invol_fused<<<dim3(NBLK), dim3(128), 0, stream>>>(
        x, w1, b1, gamma, beta, mean, var, w2, b2, out);
}

// Round 9
// 168.925 us; speedup vs baseline: 1.2304x; 1.0590x over previous
//
#include <hip/hip_runtime.h>

// Involution (B=8, H=W=192, C=64, G=4, K=3, R=4) — round 12.
// R10/R11 post-mortem: BOTH x-through-LDS variants (block-barrier and
// wave-private) lost the same ~35us: the stage->read chain serializes
// (first ds_read waits lgkmcnt on all ds_writes, each waiting vmcnt on
// its load) with zero FMA overlap. R6's strided-direct Phase A loads
// pipeline per-c4 with the w1 FMA chain — keep them. R11's bank-conflict
// count (294912) confirms the transpose writes weren't clean either.
// Harness plateau 172-179 across 4 structures while profiled swung
// 73-112 => large non-kernel component; R6/R8 structure is best.
// R12: ADJACENT column pairs in Phase B. Thread owns cols (2w, 2w+1):
// tap sets overlap -> 4 tap-cols {2w-1..2w+2} instead of 6, ring
// rg[4][4] = 64 VGPR (was 96), loads/region 6->4 (-33% VMEM insts),
// FMAs unchanged (shared taps reused from registers). Waves tile
// contiguously (wave0 cols 0-7, wave1 8-15): distinct bytes/row -17%.
// kq reads become 2-way bank-aliased (wslot stride 288B) — free.
// Rest = R6/R8 proven: strided-direct Phase A, mask-0 fences,
// B-prologue before the single barrier, (128,2), XCD swizzle.
// GATES: VGPR 85-105 (>120 = pressure regression), WRITE == 73728,
// conflicts ~0. Predict profiled 73 -> 58-68us, harness -> 160-170.
// If profiled drops but harness flat ~173 => overhead-dilution confirmed.

#define B_   8
#define H_   192
#define W_   192
#define CR_  16
#define TH_  8
#define TW_  16
#define TILES_X (W_/TW_)                    // 12
#define TILES_PER_IMG (TILES_X*(H_/TH_))    // 288
#define NBLK (B_*TILES_PER_IMG)             // 2304
#define NPIX (TH_*TW_)                      // 128

constexpr float BN_EPS = 1e-3f;

__device__ __forceinline__ float4 mask4(float4 k, bool v) {
    k.x = v ? k.x : 0.f;
    k.y = v ? k.y : 0.f;
    k.z = v ? k.z : 0.f;
    k.w = v ? k.w : 0.f;
    return k;
}

__device__ __forceinline__ void fma4(float4& a, const float4 k, const float4 x) {
    a.x = fmaf(k.x, x.x, a.x);
    a.y = fmaf(k.y, x.y, a.y);
    a.z = fmaf(k.z, x.z, a.z);
    a.w = fmaf(k.w, x.w, a.w);
}

// Load row R (clamped) into ring slot S: 4 tap-columns {2w-1..2w+2}.
// Validity bit per slot in rv (rows shared by both output columns).
#define LROWS(S, R)                                                         \
    do {                                                                    \
        int rr_ = (R);                                                      \
        if (!INTERIOR) {                                                    \
            if ((unsigned)rr_ < (unsigned)H_) rv |= (1 << (S));             \
            else                              rv &= ~(1 << (S));            \
            rr_ = rr_ < 0 ? 0 : (rr_ >= H_ ? H_ - 1 : rr_);                 \
        }                                                                   \
        const int rb_ = rr_ * (W_ * 16);                                    \
        rg[S][0] = x4[rb_ + co[0]];                                         \
        rg[S][1] = x4[rb_ + co[1]];                                         \
        rg[S][2] = x4[rb_ + co[2]];                                         \
        rg[S][3] = x4[rb_ + co[3]];                                         \
    } while (0)

// Compute pixel row th0+I for output cols wA=2w (taps 0..2) and
// wB=2w+1 (taps 1..3) from ring slots (I..I+2)&3.
#define COMP(I)                                                             \
    do {                                                                    \
        const float4* kqA_ = &s_kern[((I) * TW_ + 2 * wslot) * 9];          \
        const float4* kqB_ = kqA_ + 9;                                      \
        float4 aA_ = make_float4(0.f, 0.f, 0.f, 0.f);                       \
        float4 aB_ = make_float4(0.f, 0.f, 0.f, 0.f);                       \
        _Pragma("unroll")                                                   \
        for (int ti_ = 0; ti_ < 3; ++ti_) {                                 \
            const int s_ = ((I) + ti_) & 3;                                 \
            _Pragma("unroll")                                               \
            for (int tj_ = 0; tj_ < 3; ++tj_) {                             \
                float4 kA_ = kqA_[ti_ * 3 + tj_];                           \
                float4 kB_ = kqB_[ti_ * 3 + tj_];                           \
                if (!INTERIOR) {                                            \
                    kA_ = mask4(kA_, (((rv >> s_) & (cm >> tj_)) & 1));     \
                    kB_ = mask4(kB_, (((rv >> s_) & (cm >> (tj_ + 1))) & 1));\
                }                                                           \
                fma4(aA_, kA_, rg[s_][tj_]);                                \
                fma4(aB_, kB_, rg[s_][tj_ + 1]);                            \
            }                                                               \
        }                                                                   \
        const int ob_ = (th0 + (I)) * (W_ * 16);                            \
        o4[ob_ + (wA << 4) + c4i] = aA_;                                    \
        o4[ob_ + (wA << 4) + 16 + c4i] = aB_;                               \
    } while (0)

#define SFENCE __builtin_amdgcn_sched_barrier(0)

template <bool INTERIOR>
__device__ __forceinline__ void phase_b(const float4* __restrict__ x4,
                                        float4* __restrict__ o4,
                                        const float4* __restrict__ s_kern,
                                        int th0, int tw0, int tid)
{
    const int wslot = tid >> 4;   // 0..7 -> output cols 2w, 2w+1
    const int c4i   = tid & 15;   // float4 channel chunk
    const int wA = tw0 + 2 * wslot;

    // 4 tap-column float4-offsets {wA-1 .. wA+2} (clamped; validity
    // zeroes the kern weight, matching zero-padding semantics).
    int co[4];
    int cm = 0xF;
    #pragma unroll
    for (int tj = 0; tj < 4; ++tj) {
        int wc = wA - 1 + tj;
        if (!INTERIOR) {
            if ((unsigned)wc >= (unsigned)W_) cm &= ~(1 << tj);
            wc = wc < 0 ? 0 : (wc >= W_ ? W_ - 1 : wc);
        }
        co[tj] = (wc << 4) + c4i;
    }

    float4 rg[4][4];   // 64 VGPR ring, all indices static
    int rv = 0xF;

    // Prologue loads BEFORE the barrier: stream while the other wave
    // finishes Phase A (global-only, no LDS dependence).
    LROWS(0, th0 - 1);
    LROWS(1, th0 + 0);
    LROWS(2, th0 + 1);
    LROWS(3, th0 + 2);

    __syncthreads();   // s_kern (both waves) now visible

    SFENCE;
    // Steady state: region i = { COMP(i), prefetch row th0+i+3 }.
    // Row th0+i+3 lands in the slot retired by COMP(i); first use is
    // COMP(i+2) — two full regions of FMA+LDS work after issue.
    COMP(0); LROWS(0, th0 + 3);
    SFENCE;
    COMP(1); LROWS(1, th0 + 4);
    SFENCE;
    COMP(2); LROWS(2, th0 + 5);
    SFENCE;
    COMP(3); LROWS(3, th0 + 6);
    SFENCE;
    COMP(4); LROWS(0, th0 + 7);
    SFENCE;
    COMP(5); LROWS(1, th0 + 8);
    SFENCE;
    COMP(6);
    COMP(7);
}

#undef LROWS
#undef COMP

__global__ __launch_bounds__(128, 2)
void invol_fused(const float* __restrict__ x,
                 const float* __restrict__ w1,
                 const float* __restrict__ b1,
                 const float* __restrict__ gamma,
                 const float* __restrict__ beta,
                 const float* __restrict__ mean,
                 const float* __restrict__ var,
                 const float* __restrict__ w2,
                 const float* __restrict__ b2,
                 float* __restrict__ out)
{
    // 128 pixels * 9 float4 (36 kern floats, tap-major, g minor) = 18 KB
    __shared__ float4 s_kern[NPIX * 9];

    const int bid = blockIdx.x;
    // XCD swizzle: 2304 = 8 * 288; each XCD owns one image for L2 locality.
    const int img = bid & 7;
    const int tin = bid >> 3;
    const int th0 = (tin / TILES_X) * TH_;
    const int tw0 = (tin % TILES_X) * TW_;
    const int tid = threadIdx.x;

    // ---------------- Phase A: kernel generation (1 thread = 1 pixel) -------
    // Strided-direct global reads, DELIBERATELY: each c4 iteration's FMAs
    // wait only on load c4 -> progressive load/FMA overlap. Both LDS-staged
    // variants (R10 block-scope, R11 wave-scope) serialized and lost ~35us.
    {
        const int r = tid >> 4, cc = tid & 15;
        const int h = th0 + r, w = tw0 + cc;
        const float4* xp = reinterpret_cast<const float4*>(
            x + (((size_t)((img * H_ + h) * W_ + w)) << 6));

        float td[CR_];
        #pragma unroll
        for (int d = 0; d < CR_; ++d) td[d] = 0.f;

        // t = x @ w1   (weight addresses wave-uniform -> s_load, SMEM pipe)
        #pragma unroll
        for (int c4 = 0; c4 < 16; ++c4) {
            const float4 xv = xp[c4];
            const float xs[4] = {xv.x, xv.y, xv.z, xv.w};
            #pragma unroll
            for (int k = 0; k < 4; ++k) {
                const float* wr = w1 + (c4 * 4 + k) * CR_;
                #pragma unroll
                for (int d = 0; d < CR_; ++d)
                    td[d] = fmaf(xs[k], wr[d], td[d]);
            }
        }

        // + b1, BN (inference), ReLU — folded affine
        #pragma unroll
        for (int d = 0; d < CR_; ++d) {
            const float a = gamma[d] * rsqrtf(var[d] + BN_EPS);
            const float c = (b1[d] - mean[d]) * a + beta[d];
            td[d] = fmaxf(fmaf(td[d], a, c), 0.f);
        }

        // kern = t @ w2 + b2  (e = tap*4 + g)
        float ke[36];
        #pragma unroll
        for (int e = 0; e < 36; ++e) ke[e] = b2[e];
        #pragma unroll
        for (int d = 0; d < CR_; ++d) {
            const float t = td[d];
            const float* wr = w2 + d * 36;
            #pragma unroll
            for (int e = 0; e < 36; ++e)
                ke[e] = fmaf(t, wr[e], ke[e]);
        }

        // stride 36 words (144 B): conflict-free b128 (measured 0 conflicts)
        float4* skq = &s_kern[tid * 9];
        #pragma unroll
        for (int t9 = 0; t9 < 9; ++t9)
            skq[t9] = make_float4(ke[t9 * 4 + 0], ke[t9 * 4 + 1],
                                  ke[t9 * 4 + 2], ke[t9 * 4 + 3]);
    }

    // ---------------- Phase B: 9-tap multiply-reduce, adjacent col pairs ----
    // (barrier is inside phase_b, after the B-prologue loads issue; the
    // interior/boundary branch is block-uniform so the barrier is legal)
    const float4* x4 = reinterpret_cast<const float4*>(x) +
                       (size_t)img * (H_ * W_ * 16);
    float4* o4 = reinterpret_cast<float4*>(out) +
                 (size_t)img * (H_ * W_ * 16);

    const bool interior = (th0 > 0) && (th0 + TH_ < H_) &&
                          (tw0 > 0) && (tw0 + TW_ < W_);
    if (interior)
        phase_b<true >(x4, o4, s_kern, th0, tw0, tid);
    else
        phase_b<false>(x4, o4, s_kern, th0, tw0, tid);
}

extern "C" void kernel_launch(void* const* d_in, const int* in_sizes, int n_in,
                              void* d_out, int out_size, void* d_ws, size_t ws_size,
                              hipStream_t stream) {
    const float* x     = (const float*)d_in[0];
    const float* w1    = (const float*)d_in[1];
    const float* b1    = (const float*)d_in[2];
    const float* gamma = (const float*)d_in[3];
    const float* beta  = (const float*)d_in[4];
    const float* mean  = (const float*)d_in[5];
    const float* var   = (const float*)d_in[6];
    const float* w2    = (const float*)d_in[7];
    const float* b2    = (const float*)d_in[8];
    float* out = (float*)d_out;

    invol_fused<<<dim3(NBLK), dim3(128), 0, stream>>>(
        x, w1, b1, gamma, beta, mean, var, w2, b2, out);
}